// Round 9
// baseline (937.834 us; speedup 1.0000x reference)
//
#include <hip/hip_runtime.h>
#include <hip/hip_bf16.h>
#include <hip/hip_fp16.h>

#define BS 256
#define CBS 1024         // threads per block in per-graph GCN kernel
#define NWAVES (CBS/64)
#define PCHUNK 2048      // edges per prep chunk (list segment stride)
#define NG 64            // NUM_GRAPHS (fixed by the problem)
#define NMAX 8192        // max nodes per graph supported in LDS histogram

__device__ __forceinline__ uint4 pack8(const float* f) {
    union { uint4 u; __half2 h[4]; } v;
    v.h[0] = __floats2half2_rn(f[0], f[1]);
    v.h[1] = __floats2half2_rn(f[2], f[3]);
    v.h[2] = __floats2half2_rn(f[4], f[5]);
    v.h[3] = __floats2half2_rn(f[6], f[7]);
    return v.u;
}

__device__ __forceinline__ void unpack8(uint4 u, float* f) {
    const __half2* h = (const __half2*)&u;
    float2 t;
    t = __half22float2(h[0]); f[0] = t.x; f[1] = t.y;
    t = __half22float2(h[1]); f[2] = t.x; f[3] = t.y;
    t = __half22float2(h[2]); f[4] = t.x; f[5] = t.y;
    t = __half22float2(h[3]); f[6] = t.x; f[7] = t.y;
}

// ---------------------------------------------------------------------------
// Kernel AB: node phase (zero aggA/aggB, graph bounds, encode -> M) +
// edge phase (chunk-compacted valid-edge list, per-chunk segments, no global
// counter).
// ---------------------------------------------------------------------------
__global__ __launch_bounds__(BS) void ab_kernel(
        const int* __restrict__ seq,
        const float* __restrict__ xcov,
        const int* __restrict__ ei,
        const int* __restrict__ batch,
        const float* __restrict__ embed,   // 6x16
        const float* __restrict__ w1,      // 17x16
        const float* __restrict__ b1,      // 16
        float* __restrict__ M,
        float* __restrict__ aggA,
        float* __restrict__ aggB,
        int* __restrict__ bnd,
        int2* __restrict__ list,
        int* __restrict__ cnt,
        int N, int E, int nch) {
    __shared__ float sE[96];
    __shared__ float sW1[272];
    __shared__ float sB1[16];
    __shared__ int2 buf[PCHUNK];
    __shared__ int lcnt;

    int tid = threadIdx.x;
    for (int i = tid; i < 96; i += BS) sE[i] = embed[i];
    for (int i = tid; i < 272; i += BS) sW1[i] = w1[i];
    if (tid < 16) sB1[tid] = b1[tid];
    __syncthreads();

    // ---- node phase ----
    int gsz = gridDim.x * BS;
    float4 z4 = make_float4(0.f, 0.f, 0.f, 0.f);
    for (int n = blockIdx.x * BS + tid; n < N; n += gsz) {
        float4* aA = (float4*)(aggA + (size_t)n * 16);
        float4* aB = (float4*)(aggB + (size_t)n * 16);
        aA[0] = z4; aA[1] = z4; aA[2] = z4; aA[3] = z4;
        aB[0] = z4; aB[1] = z4; aB[2] = z4; aB[3] = z4;

        int b = batch[n];
        if (n == 0) {
            for (int g = 0; g <= b; g++) bnd[g] = 0;
        } else {
            int pb = batch[n - 1];
            for (int g = pb + 1; g <= b; g++) bnd[g] = n;
        }
        if (n == N - 1) {
            for (int g = b + 1; g <= NG; g++) bnd[g] = N;
        }

        const int4* t4 = (const int4*)(seq + (size_t)n * 64);
        int c1 = 0, c2 = 0, c3 = 0, c4 = 0, c5 = 0;
#pragma unroll
        for (int i = 0; i < 16; i++) {
            int4 v = t4[i];
            c1 += (v.x == 1) + (v.y == 1) + (v.z == 1) + (v.w == 1);
            c2 += (v.x == 2) + (v.y == 2) + (v.z == 2) + (v.w == 2);
            c3 += (v.x == 3) + (v.y == 3) + (v.z == 3) + (v.w == 3);
            c4 += (v.x == 4) + (v.y == 4) + (v.z == 4) + (v.w == 4);
            c5 += (v.x == 5) + (v.y == 5) + (v.z == 5) + (v.w == 5);
        }
        float f1 = (float)c1, f2 = (float)c2, f3 = (float)c3, f4 = (float)c4, f5 = (float)c5;
        float tot = f1 + f2 + f3 + f4 + f5;
        float inv = 1.0f / fmaxf(tot, 1.0f);
        float h[16];
#pragma unroll
        for (int j = 0; j < 16; j++)
            h[j] = (f1 * sE[16 + j] + f2 * sE[32 + j] + f3 * sE[48 + j] +
                    f4 * sE[64 + j] + f5 * sE[80 + j]) * inv;
        float xc = xcov[n];
        float o[16];
#pragma unroll
        for (int j = 0; j < 16; j++) o[j] = sB1[j] + xc * sW1[256 + j];
#pragma unroll
        for (int k = 0; k < 16; k++) {
            float hk = h[k];
#pragma unroll
            for (int j = 0; j < 16; j++) o[j] += hk * sW1[k * 16 + j];
        }
        float4* mr = (float4*)(M + (size_t)n * 16);
        mr[0] = make_float4(o[0], o[1], o[2], o[3]);
        mr[1] = make_float4(o[4], o[5], o[6], o[7]);
        mr[2] = make_float4(o[8], o[9], o[10], o[11]);
        mr[3] = make_float4(o[12], o[13], o[14], o[15]);
    }

    // ---- edge phase: per-chunk compaction into fixed segments ----
    for (int ci = blockIdx.x; ci < nch; ci += gridDim.x) {
        __syncthreads();
        if (tid == 0) lcnt = 0;
        __syncthreads();
        int e0 = ci * PCHUNK;
#pragma unroll
        for (int k = 0; k < PCHUNK / (BS * 4); k++) {
            int idx = e0 + (k * BS + tid) * 4;
            if (idx + 3 < E) {
                int4 s4 = *(const int4*)(ei + idx);
                int4 d4 = *(const int4*)(ei + E + idx);
                int bs0 = batch[s4.x], bd0 = batch[d4.x];
                int bs1 = batch[s4.y], bd1 = batch[d4.y];
                int bs2 = batch[s4.z], bd2 = batch[d4.z];
                int bs3 = batch[s4.w], bd3 = batch[d4.w];
                if (bs0 == bd0) buf[atomicAdd(&lcnt, 1)] = make_int2(s4.x, d4.x);
                if (bs1 == bd1) buf[atomicAdd(&lcnt, 1)] = make_int2(s4.y, d4.y);
                if (bs2 == bd2) buf[atomicAdd(&lcnt, 1)] = make_int2(s4.z, d4.z);
                if (bs3 == bd3) buf[atomicAdd(&lcnt, 1)] = make_int2(s4.w, d4.w);
            } else {
                for (int j = 0; j < 4; j++) {
                    int e = idx + j;
                    if (e < E) {
                        int s = ei[e], d = ei[E + e];
                        if (batch[s] == batch[d])
                            buf[atomicAdd(&lcnt, 1)] = make_int2(s, d);
                    }
                }
            }
        }
        __syncthreads();
        int c = lcnt;
        int2* seg = list + (size_t)ci * PCHUNK;
        for (int i = tid; i < c; i += BS) seg[i] = buf[i];
        if (tid == 0) cnt[ci] = c;
    }
}

// ---------------------------------------------------------------------------
// Kernel C: one block per graph. Block-local barriers only.
//   scan1: LDS deg histogram -> dinv (LDS)
//   scan2: agg1 atomics into aggA   -> fin1: M <- relu(di*(aggA+di*M))@w2+b2
//   scan3: agg2 atomics into aggB   -> fin2: H2 -> P,Q (f16)
// ---------------------------------------------------------------------------
__global__ __launch_bounds__(CBS) void graph_gcn_kernel(
        const int2* __restrict__ list,
        const int* __restrict__ cnt,
        const int* __restrict__ bnd,
        float* __restrict__ M,
        float* __restrict__ aggA,
        float* __restrict__ aggB,
        const float* __restrict__ w2,      // 16x16
        const float* __restrict__ b2,      // 16
        const float* __restrict__ we1,     // 37x16
        ushort* __restrict__ Pf,
        ushort* __restrict__ Qf,
        int nch) {
    __shared__ int hist[NMAX];            // int counts, then float dinv (aliased)
    __shared__ float sW2[256];
    __shared__ float sB2[16];
    __shared__ float sWe1[512];

    int tid = threadIdx.x;
    int g = blockIdx.x;
    int lo = bnd[g], hi = bnd[g + 1];
    int ng = hi - lo;
    float* dinvL = (float*)hist;

    for (int i = tid; i < 256; i += CBS) sW2[i] = w2[i];
    for (int i = tid; i < 512; i += CBS) sWe1[i] = we1[i];
    if (tid < 16) sB2[tid] = b2[tid];
    for (int i = tid; i < NMAX; i += CBS) hist[i] = 0;
    __syncthreads();

    if (ng <= 0) return;    // empty graph: nothing to do (uniform exit, after barrier use)

    int wave = tid >> 6, lane = tid & 63;

    // ---- scan1: degree histogram ----
    for (int ci = wave; ci < nch; ci += NWAVES) {
        int c = cnt[ci];
        const int2* seg = list + (size_t)ci * PCHUNK;
        for (int j = lane; j < c; j += 64) {
            int2 p = seg[j];
            if (p.x >= lo && p.x < hi) atomicAdd(&hist[p.x - lo], 1);
        }
    }
    __syncthreads();
    // convert counts -> dinv in place
    for (int i = tid; i < ng; i += CBS) {
        float dg = (float)hist[i] + 1.0f + 1e-8f;
        float v = 1.0f / sqrtf(dg);
        __syncthreads;  // no-op statement guard (no actual sync needed per-element)
        dinvL[i] = v;
    }
    __syncthreads();

    // ---- scan2: agg1 -> aggA ----
    for (int ci = wave; ci < nch; ci += NWAVES) {
        int c = cnt[ci];
        const int2* seg = list + (size_t)ci * PCHUNK;
        for (int j = lane; j < c; j += 64) {
            int2 p = seg[j];
            if (p.x >= lo && p.x < hi) {
                float cc = dinvL[p.y - lo];
                const float4* m4 = (const float4*)(M + (size_t)p.y * 16);
                float4 v0 = m4[0], v1 = m4[1], v2 = m4[2], v3 = m4[3];
                float* a = aggA + (size_t)p.x * 16;
                atomicAdd(a + 0,  cc * v0.x); atomicAdd(a + 1,  cc * v0.y);
                atomicAdd(a + 2,  cc * v0.z); atomicAdd(a + 3,  cc * v0.w);
                atomicAdd(a + 4,  cc * v1.x); atomicAdd(a + 5,  cc * v1.y);
                atomicAdd(a + 6,  cc * v1.z); atomicAdd(a + 7,  cc * v1.w);
                atomicAdd(a + 8,  cc * v2.x); atomicAdd(a + 9,  cc * v2.y);
                atomicAdd(a + 10, cc * v2.z); atomicAdd(a + 11, cc * v2.w);
                atomicAdd(a + 12, cc * v3.x); atomicAdd(a + 13, cc * v3.y);
                atomicAdd(a + 14, cc * v3.z); atomicAdd(a + 15, cc * v3.w);
            }
        }
    }
    __syncthreads();

    // ---- fin1 ----
    for (int n = lo + tid; n < hi; n += CBS) {
        float di = dinvL[n - lo];
        float4* mr = (float4*)(M + (size_t)n * 16);
        const float4* ar = (const float4*)(aggA + (size_t)n * 16);
        float h[16];
#pragma unroll
        for (int q = 0; q < 4; q++) {
            float4 m = mr[q], a = ar[q];
            h[q*4+0] = fmaxf(di * (a.x + di * m.x), 0.0f);
            h[q*4+1] = fmaxf(di * (a.y + di * m.y), 0.0f);
            h[q*4+2] = fmaxf(di * (a.z + di * m.z), 0.0f);
            h[q*4+3] = fmaxf(di * (a.w + di * m.w), 0.0f);
        }
        float o[16];
#pragma unroll
        for (int j = 0; j < 16; j++) o[j] = sB2[j];
#pragma unroll
        for (int k = 0; k < 16; k++) {
            float hk = h[k];
#pragma unroll
            for (int j = 0; j < 16; j++) o[j] += hk * sW2[k * 16 + j];
        }
        mr[0] = make_float4(o[0], o[1], o[2], o[3]);
        mr[1] = make_float4(o[4], o[5], o[6], o[7]);
        mr[2] = make_float4(o[8], o[9], o[10], o[11]);
        mr[3] = make_float4(o[12], o[13], o[14], o[15]);
    }
    __syncthreads();

    // ---- scan3: agg2 -> aggB ----
    for (int ci = wave; ci < nch; ci += NWAVES) {
        int c = cnt[ci];
        const int2* seg = list + (size_t)ci * PCHUNK;
        for (int j = lane; j < c; j += 64) {
            int2 p = seg[j];
            if (p.x >= lo && p.x < hi) {
                float cc = dinvL[p.y - lo];
                const float4* m4 = (const float4*)(M + (size_t)p.y * 16);
                float4 v0 = m4[0], v1 = m4[1], v2 = m4[2], v3 = m4[3];
                float* a = aggB + (size_t)p.x * 16;
                atomicAdd(a + 0,  cc * v0.x); atomicAdd(a + 1,  cc * v0.y);
                atomicAdd(a + 2,  cc * v0.z); atomicAdd(a + 3,  cc * v0.w);
                atomicAdd(a + 4,  cc * v1.x); atomicAdd(a + 5,  cc * v1.y);
                atomicAdd(a + 6,  cc * v1.z); atomicAdd(a + 7,  cc * v1.w);
                atomicAdd(a + 8,  cc * v2.x); atomicAdd(a + 9,  cc * v2.y);
                atomicAdd(a + 10, cc * v2.z); atomicAdd(a + 11, cc * v2.w);
                atomicAdd(a + 12, cc * v3.x); atomicAdd(a + 13, cc * v3.y);
                atomicAdd(a + 14, cc * v3.z); atomicAdd(a + 15, cc * v3.w);
            }
        }
    }
    __syncthreads();

    // ---- fin2: H2 -> P,Q ----
    for (int n = lo + tid; n < hi; n += CBS) {
        float di = dinvL[n - lo];
        const float4* mr = (const float4*)(M + (size_t)n * 16);
        const float4* ar = (const float4*)(aggB + (size_t)n * 16);
        float h[16];
#pragma unroll
        for (int q = 0; q < 4; q++) {
            float4 m = mr[q], a = ar[q];
            h[q*4+0] = fmaxf(di * (a.x + di * m.x), 0.0f);
            h[q*4+1] = fmaxf(di * (a.y + di * m.y), 0.0f);
            h[q*4+2] = fmaxf(di * (a.z + di * m.z), 0.0f);
            h[q*4+3] = fmaxf(di * (a.w + di * m.w), 0.0f);
        }
        float p[16], q[16];
#pragma unroll
        for (int j = 0; j < 16; j++) { p[j] = 0.f; q[j] = 0.f; }
#pragma unroll
        for (int k = 0; k < 16; k++) {
            float hk = h[k];
#pragma unroll
            for (int j = 0; j < 16; j++) {
                p[j] += hk * sWe1[k * 16 + j];
                q[j] += hk * sWe1[(16 + k) * 16 + j];
            }
        }
        uint4* pr = (uint4*)(Pf + (size_t)n * 16);
        pr[0] = pack8(p); pr[1] = pack8(p + 8);
        uint4* qr = (uint4*)(Qf + (size_t)n * 16);
        qr[0] = pack8(q); qr[1] = pack8(q + 8);
    }
}

// ---------------------------------------------------------------------------
// Edge MLP (1 edge/thread, R7 known-good). NT streams for ei/eattr/out.
// ---------------------------------------------------------------------------
__global__ __launch_bounds__(BS) void edge_mlp_kernel(
        const int* __restrict__ ei,
        const ushort* __restrict__ Pf,
        const ushort* __restrict__ Qf,
        const float* __restrict__ eattr,   // E x 5 f32
        const float* __restrict__ we1,     // 37x16 f32
        const float* __restrict__ be1,     // 16
        const float* __restrict__ we2,     // 16
        const float* __restrict__ be2,     // 1
        float* __restrict__ out, int E) {
    __shared__ float sC[80];   // we1 rows 32..36
    __shared__ float sB[16];
    __shared__ float sV[16];
    __shared__ float sb2;
    int tid = threadIdx.x;
    if (tid < 80) sC[tid] = we1[512 + tid];
    if (tid < 16) { sB[tid] = be1[tid]; sV[tid] = we2[tid]; }
    if (tid == 0) sb2 = be2[0];
    __syncthreads();
    int e = blockIdx.x * BS + tid;
    if (e >= E) return;
    int s = __builtin_nontemporal_load(ei + e);
    int d = __builtin_nontemporal_load(ei + E + e);
    const uint4* pr = (const uint4*)(Pf + (size_t)s * 16);
    const uint4* qr = (const uint4*)(Qf + (size_t)d * 16);
    uint4 pa = pr[0], pb = pr[1];
    uint4 qa = qr[0], qb = qr[1];
    const float* ea = eattr + (size_t)e * 5;
    float a0 = __builtin_nontemporal_load(ea + 0);
    float a1 = __builtin_nontemporal_load(ea + 1);
    float a2 = __builtin_nontemporal_load(ea + 2);
    float a3 = __builtin_nontemporal_load(ea + 3);
    float a4 = __builtin_nontemporal_load(ea + 4);

    float p[16], q[16];
    unpack8(pa, p); unpack8(pb, p + 8);
    unpack8(qa, q); unpack8(qb, q + 8);

    float lg = sb2;
#pragma unroll
    for (int j = 0; j < 16; j++) {
        float acc = sB[j] + p[j] + q[j] +
                    a0 * sC[j] + a1 * sC[16 + j] + a2 * sC[32 + j] +
                    a3 * sC[48 + j] + a4 * sC[64 + j];
        lg += fmaxf(acc, 0.0f) * sV[j];
    }
    __builtin_nontemporal_store(lg, out + e);
}

// ---------------------------------------------------------------------------
extern "C" void kernel_launch(void* const* d_in, const int* in_sizes, int n_in,
                              void* d_out, int out_size, void* d_ws, size_t ws_size,
                              hipStream_t stream) {
    const int* seq     = (const int*)d_in[0];
    const float* xcov  = (const float*)d_in[1];
    const int* ei      = (const int*)d_in[2];
    const float* eattr = (const float*)d_in[3];
    const int* batch   = (const int*)d_in[4];
    const float* embed = (const float*)d_in[5];
    const float* w1    = (const float*)d_in[6];
    const float* b1    = (const float*)d_in[7];
    const float* w2    = (const float*)d_in[8];
    const float* b2    = (const float*)d_in[9];
    const float* we1   = (const float*)d_in[10];
    const float* be1   = (const float*)d_in[11];
    const float* we2   = (const float*)d_in[12];
    const float* be2   = (const float*)d_in[13];
    float* out         = (float*)d_out;   // fp32 output

    int N = in_sizes[1];
    int E = in_sizes[2] / 2;
    int nch = (E + PCHUNK - 1) / PCHUNK;

    char* ws = (char*)d_ws;
    size_t off = 0;
    auto alloc = [&](size_t bytes) -> void* {
        void* p = ws + off;
        off += (bytes + 255) & ~(size_t)255;
        return p;
    };
    float* M     = (float*)alloc((size_t)N * 16 * sizeof(float));
    float* aggA  = (float*)alloc((size_t)N * 16 * sizeof(float));
    float* aggB  = (float*)alloc((size_t)N * 16 * sizeof(float));
    ushort* Pf   = (ushort*)alloc((size_t)N * 16 * sizeof(ushort));
    ushort* Qf   = (ushort*)alloc((size_t)N * 16 * sizeof(ushort));
    int* bndg    = (int*)alloc((NG + 1) * sizeof(int));
    int* cnt     = (int*)alloc((size_t)nch * sizeof(int));
    int2* list   = (int2*)alloc((size_t)nch * PCHUNK * sizeof(int2));

    ab_kernel<<<nch, BS, 0, stream>>>(seq, xcov, ei, batch, embed, w1, b1,
                                      M, aggA, aggB, bndg, list, cnt, N, E, nch);
    graph_gcn_kernel<<<NG, CBS, 0, stream>>>(list, cnt, bndg, M, aggA, aggB,
                                             w2, b2, we1, Pf, Qf, nch);
    int ge = (E + BS - 1) / BS;
    edge_mlp_kernel<<<ge, BS, 0, stream>>>(ei, Pf, Qf, eattr, we1, be1, we2, be2, out, E);
}

// Round 10
// 676.789 us; speedup vs baseline: 1.3857x; 1.3857x over previous
//
#include <hip/hip_runtime.h>
#include <hip/hip_bf16.h>
#include <hip/hip_fp16.h>

#define BS 256
#define CBS 1024         // threads per block in per-graph GCN kernel
#define NG 64            // NUM_GRAPHS (fixed by the problem)
#define NMAX 4096        // max nodes per graph (mean 1563, sigma ~39 -> 64 sigma)
#define SEGCAP 4096      // max valid edges per graph (mean ~780)

__device__ __forceinline__ uint4 pack8(const float* f) {
    union { uint4 u; __half2 h[4]; } v;
    v.h[0] = __floats2half2_rn(f[0], f[1]);
    v.h[1] = __floats2half2_rn(f[2], f[3]);
    v.h[2] = __floats2half2_rn(f[4], f[5]);
    v.h[3] = __floats2half2_rn(f[6], f[7]);
    return v.u;
}

__device__ __forceinline__ void unpack8(uint4 u, float* f) {
    const __half2* h = (const __half2*)&u;
    float2 t;
    t = __half22float2(h[0]); f[0] = t.x; f[1] = t.y;
    t = __half22float2(h[1]); f[2] = t.x; f[3] = t.y;
    t = __half22float2(h[2]); f[4] = t.x; f[5] = t.y;
    t = __half22float2(h[3]); f[6] = t.x; f[7] = t.y;
}

// ---------------------------------------------------------------------------
// K1: zero aggPQ/gcnt, graph bounds from sorted batch, encode -> M
// ---------------------------------------------------------------------------
__global__ __launch_bounds__(BS) void encode_kernel(
        const int* __restrict__ seq,
        const float* __restrict__ xcov,
        const int* __restrict__ batch,
        const float* __restrict__ embed,   // 6x16
        const float* __restrict__ w1,      // 17x16
        const float* __restrict__ b1,      // 16
        float* __restrict__ M,
        float* __restrict__ aggPQ,
        int* __restrict__ gcnt,            // 64*16 padded
        int* __restrict__ bnd, int N) {
    __shared__ float sE[96];
    __shared__ float sW1[272];
    __shared__ float sB1[16];
    int tid = threadIdx.x;
    for (int i = tid; i < 96; i += BS) sE[i] = embed[i];
    for (int i = tid; i < 272; i += BS) sW1[i] = w1[i];
    if (tid < 16) sB1[tid] = b1[tid];
    __syncthreads();

    if (blockIdx.x == 0 && tid < NG) gcnt[tid * 16] = 0;

    int n = blockIdx.x * BS + tid;
    if (n >= N) return;

    float4 z4 = make_float4(0.f, 0.f, 0.f, 0.f);
    float4* ar = (float4*)(aggPQ + (size_t)n * 16);
    ar[0] = z4; ar[1] = z4; ar[2] = z4; ar[3] = z4;

    int b = batch[n];
    if (n == 0) {
        for (int g = 0; g <= b; g++) bnd[g] = 0;
    } else {
        int pb = batch[n - 1];
        for (int g = pb + 1; g <= b; g++) bnd[g] = n;
    }
    if (n == N - 1) {
        for (int g = b + 1; g <= NG; g++) bnd[g] = N;
    }

    const int4* t4 = (const int4*)(seq + (size_t)n * 64);
    int c1 = 0, c2 = 0, c3 = 0, c4 = 0, c5 = 0;
#pragma unroll
    for (int i = 0; i < 16; i++) {
        int4 v = t4[i];
        c1 += (v.x == 1) + (v.y == 1) + (v.z == 1) + (v.w == 1);
        c2 += (v.x == 2) + (v.y == 2) + (v.z == 2) + (v.w == 2);
        c3 += (v.x == 3) + (v.y == 3) + (v.z == 3) + (v.w == 3);
        c4 += (v.x == 4) + (v.y == 4) + (v.z == 4) + (v.w == 4);
        c5 += (v.x == 5) + (v.y == 5) + (v.z == 5) + (v.w == 5);
    }
    float f1 = (float)c1, f2 = (float)c2, f3 = (float)c3, f4 = (float)c4, f5 = (float)c5;
    float tot = f1 + f2 + f3 + f4 + f5;
    float inv = 1.0f / fmaxf(tot, 1.0f);
    float h[16];
#pragma unroll
    for (int j = 0; j < 16; j++)
        h[j] = (f1 * sE[16 + j] + f2 * sE[32 + j] + f3 * sE[48 + j] +
                f4 * sE[64 + j] + f5 * sE[80 + j]) * inv;
    float xc = xcov[n];
    float o[16];
#pragma unroll
    for (int j = 0; j < 16; j++) o[j] = sB1[j] + xc * sW1[256 + j];
#pragma unroll
    for (int k = 0; k < 16; k++) {
        float hk = h[k];
#pragma unroll
        for (int j = 0; j < 16; j++) o[j] += hk * sW1[k * 16 + j];
    }
    float4* mr = (float4*)(M + (size_t)n * 16);
    mr[0] = make_float4(o[0], o[1], o[2], o[3]);
    mr[1] = make_float4(o[4], o[5], o[6], o[7]);
    mr[2] = make_float4(o[8], o[9], o[10], o[11]);
    mr[3] = make_float4(o[12], o[13], o[14], o[15]);
}

// ---------------------------------------------------------------------------
// K2: prep — validity via LDS bound search, bucket valid edges per graph.
// 64 line-padded counters -> low contention.
// ---------------------------------------------------------------------------
__device__ __forceinline__ int find_graph(const int* bnd, int s) {
    int g = 0;
#pragma unroll
    for (int step = 32; step; step >>= 1) {
        int c = g + step;
        if (c <= NG - 1 && bnd[c] <= s) g = c;
    }
    return g;
}

__global__ __launch_bounds__(BS) void prep_kernel(
        const int* __restrict__ ei,
        const int* __restrict__ bndg,
        int2* __restrict__ glist,
        int* __restrict__ gcnt, int E) {
    __shared__ int sBnd[NG + 1];
    int tid = threadIdx.x;
    if (tid <= NG) sBnd[tid] = bndg[tid];
    __syncthreads();

    int idx = (blockIdx.x * BS + tid) * 4;
    if (idx + 3 < E) {
        int4 s4 = *(const int4*)(ei + idx);
        int4 d4 = *(const int4*)(ei + E + idx);
#pragma unroll
        for (int j = 0; j < 4; j++) {
            int s = (&s4.x)[j], d = (&d4.x)[j];
            int g = find_graph(sBnd, s);
            if (d >= sBnd[g] && d < sBnd[g + 1]) {
                int pos = atomicAdd(&gcnt[g * 16], 1);
                if (pos < SEGCAP) glist[(size_t)g * SEGCAP + pos] = make_int2(s, d);
            }
        }
    } else {
        for (int j = 0; j < 4; j++) {
            int e = idx + j;
            if (e < E) {
                int s = ei[e], d = ei[E + e];
                int g = find_graph(sBnd, s);
                if (d >= sBnd[g] && d < sBnd[g + 1]) {
                    int pos = atomicAdd(&gcnt[g * 16], 1);
                    if (pos < SEGCAP) glist[(size_t)g * SEGCAP + pos] = make_int2(s, d);
                }
            }
        }
    }
}

// ---------------------------------------------------------------------------
// K3: one block per graph, reading ONLY its own edge bucket (~780 edges).
//   scan1: LDS deg histogram -> dinv (LDS, in place)
//   agg1 (global atomics, graph-exclusive rows) -> fin1 (M <- H1@w2+b2, agg<-0)
//   agg2 -> fin2 (H2 -> P|Q f16 packed into the agg row: 64 B = P(32)|Q(32))
// ---------------------------------------------------------------------------
__global__ __launch_bounds__(CBS) void graph_gcn_kernel(
        const int2* __restrict__ glist,
        const int* __restrict__ gcnt,
        const int* __restrict__ bnd,
        float* __restrict__ M,
        float* __restrict__ aggPQ,
        const float* __restrict__ w2,      // 16x16
        const float* __restrict__ b2,      // 16
        const float* __restrict__ we1) {   // 37x16 (rows 0..31 used)
    __shared__ int hist[NMAX];
    __shared__ float sW2[256];
    __shared__ float sB2[16];
    __shared__ float sWe1[512];

    int tid = threadIdx.x;
    int g = blockIdx.x;
    int lo = bnd[g], hi = bnd[g + 1];
    int ng = hi - lo;
    if (ng > NMAX) ng = NMAX;   // statistically impossible; guard OOB
    float* dinvL = (float*)hist;

    for (int i = tid; i < 256; i += CBS) sW2[i] = w2[i];
    for (int i = tid; i < 512; i += CBS) sWe1[i] = we1[i];
    if (tid < 16) sB2[tid] = b2[tid];
    for (int i = tid; i < NMAX; i += CBS) hist[i] = 0;
    __syncthreads();

    if (ng <= 0) return;   // uniform whole-block exit

    int myCnt = gcnt[g * 16];
    if (myCnt > SEGCAP) myCnt = SEGCAP;
    const int2* seg = glist + (size_t)g * SEGCAP;

    // ---- scan1: degree histogram (LDS atomics) ----
    for (int j = tid; j < myCnt; j += CBS) {
        int2 e = seg[j];
        atomicAdd(&hist[e.x - lo], 1);
    }
    __syncthreads();
    for (int i = tid; i < ng; i += CBS) {
        float dg = (float)hist[i] + 1.0f + 1e-8f;
        dinvL[i] = 1.0f / sqrtf(dg);
    }
    __syncthreads();

    // ---- agg1 ----
    for (int j = tid; j < myCnt; j += CBS) {
        int2 e = seg[j];
        float cc = dinvL[e.y - lo];
        const float4* m4 = (const float4*)(M + (size_t)e.y * 16);
        float4 v0 = m4[0], v1 = m4[1], v2 = m4[2], v3 = m4[3];
        float* a = aggPQ + (size_t)e.x * 16;
        atomicAdd(a + 0,  cc * v0.x); atomicAdd(a + 1,  cc * v0.y);
        atomicAdd(a + 2,  cc * v0.z); atomicAdd(a + 3,  cc * v0.w);
        atomicAdd(a + 4,  cc * v1.x); atomicAdd(a + 5,  cc * v1.y);
        atomicAdd(a + 6,  cc * v1.z); atomicAdd(a + 7,  cc * v1.w);
        atomicAdd(a + 8,  cc * v2.x); atomicAdd(a + 9,  cc * v2.y);
        atomicAdd(a + 10, cc * v2.z); atomicAdd(a + 11, cc * v2.w);
        atomicAdd(a + 12, cc * v3.x); atomicAdd(a + 13, cc * v3.y);
        atomicAdd(a + 14, cc * v3.z); atomicAdd(a + 15, cc * v3.w);
    }
    __syncthreads();

    // ---- fin1: M <- relu(di*(agg+di*M))@w2+b2 ; agg <- 0 ----
    float4 z4 = make_float4(0.f, 0.f, 0.f, 0.f);
    for (int n = lo + tid; n < hi; n += CBS) {
        float di = dinvL[n - lo];
        float4* mr = (float4*)(M + (size_t)n * 16);
        float4* ar = (float4*)(aggPQ + (size_t)n * 16);
        float h[16];
#pragma unroll
        for (int q = 0; q < 4; q++) {
            float4 m = mr[q], a = ar[q];
            h[q*4+0] = fmaxf(di * (a.x + di * m.x), 0.0f);
            h[q*4+1] = fmaxf(di * (a.y + di * m.y), 0.0f);
            h[q*4+2] = fmaxf(di * (a.z + di * m.z), 0.0f);
            h[q*4+3] = fmaxf(di * (a.w + di * m.w), 0.0f);
        }
        ar[0] = z4; ar[1] = z4; ar[2] = z4; ar[3] = z4;
        float o[16];
#pragma unroll
        for (int j = 0; j < 16; j++) o[j] = sB2[j];
#pragma unroll
        for (int k = 0; k < 16; k++) {
            float hk = h[k];
#pragma unroll
            for (int j = 0; j < 16; j++) o[j] += hk * sW2[k * 16 + j];
        }
        mr[0] = make_float4(o[0], o[1], o[2], o[3]);
        mr[1] = make_float4(o[4], o[5], o[6], o[7]);
        mr[2] = make_float4(o[8], o[9], o[10], o[11]);
        mr[3] = make_float4(o[12], o[13], o[14], o[15]);
    }
    __syncthreads();

    // ---- agg2 ----
    for (int j = tid; j < myCnt; j += CBS) {
        int2 e = seg[j];
        float cc = dinvL[e.y - lo];
        const float4* m4 = (const float4*)(M + (size_t)e.y * 16);
        float4 v0 = m4[0], v1 = m4[1], v2 = m4[2], v3 = m4[3];
        float* a = aggPQ + (size_t)e.x * 16;
        atomicAdd(a + 0,  cc * v0.x); atomicAdd(a + 1,  cc * v0.y);
        atomicAdd(a + 2,  cc * v0.z); atomicAdd(a + 3,  cc * v0.w);
        atomicAdd(a + 4,  cc * v1.x); atomicAdd(a + 5,  cc * v1.y);
        atomicAdd(a + 6,  cc * v1.z); atomicAdd(a + 7,  cc * v1.w);
        atomicAdd(a + 8,  cc * v2.x); atomicAdd(a + 9,  cc * v2.y);
        atomicAdd(a + 10, cc * v2.z); atomicAdd(a + 11, cc * v2.w);
        atomicAdd(a + 12, cc * v3.x); atomicAdd(a + 13, cc * v3.y);
        atomicAdd(a + 14, cc * v3.z); atomicAdd(a + 15, cc * v3.w);
    }
    __syncthreads();

    // ---- fin2: H2 -> P|Q (f16), overwriting the agg row (thread-exclusive) ----
    for (int n = lo + tid; n < hi; n += CBS) {
        float di = dinvL[n - lo];
        const float4* mr = (const float4*)(M + (size_t)n * 16);
        float4* ar = (float4*)(aggPQ + (size_t)n * 16);
        float h[16];
#pragma unroll
        for (int q = 0; q < 4; q++) {
            float4 m = mr[q], a = ar[q];
            h[q*4+0] = fmaxf(di * (a.x + di * m.x), 0.0f);
            h[q*4+1] = fmaxf(di * (a.y + di * m.y), 0.0f);
            h[q*4+2] = fmaxf(di * (a.z + di * m.z), 0.0f);
            h[q*4+3] = fmaxf(di * (a.w + di * m.w), 0.0f);
        }
        float p[16], q[16];
#pragma unroll
        for (int j = 0; j < 16; j++) { p[j] = 0.f; q[j] = 0.f; }
#pragma unroll
        for (int k = 0; k < 16; k++) {
            float hk = h[k];
#pragma unroll
            for (int j = 0; j < 16; j++) {
                p[j] += hk * sWe1[k * 16 + j];
                q[j] += hk * sWe1[(16 + k) * 16 + j];
            }
        }
        uint4* pr = (uint4*)ar;
        pr[0] = pack8(p); pr[1] = pack8(p + 8);
        pr[2] = pack8(q); pr[3] = pack8(q + 8);
    }
}

// ---------------------------------------------------------------------------
// K4: edge MLP (1 edge/thread). P at row*64, Q at row*64+32 in PQ buffer.
// ---------------------------------------------------------------------------
__global__ __launch_bounds__(BS) void edge_mlp_kernel(
        const int* __restrict__ ei,
        const char* __restrict__ PQ,       // N x 64 B rows: P(32)|Q(32) f16
        const float* __restrict__ eattr,   // E x 5 f32
        const float* __restrict__ we1,     // 37x16 f32
        const float* __restrict__ be1,     // 16
        const float* __restrict__ we2,     // 16
        const float* __restrict__ be2,     // 1
        float* __restrict__ out, int E) {
    __shared__ float sC[80];   // we1 rows 32..36
    __shared__ float sB[16];
    __shared__ float sV[16];
    __shared__ float sb2;
    int tid = threadIdx.x;
    if (tid < 80) sC[tid] = we1[512 + tid];
    if (tid < 16) { sB[tid] = be1[tid]; sV[tid] = we2[tid]; }
    if (tid == 0) sb2 = be2[0];
    __syncthreads();
    int e = blockIdx.x * BS + tid;
    if (e >= E) return;
    int s = __builtin_nontemporal_load(ei + e);
    int d = __builtin_nontemporal_load(ei + E + e);
    const uint4* pr = (const uint4*)(PQ + (size_t)s * 64);
    const uint4* qr = (const uint4*)(PQ + (size_t)d * 64 + 32);
    uint4 pa = pr[0], pb = pr[1];
    uint4 qa = qr[0], qb = qr[1];
    const float* ea = eattr + (size_t)e * 5;
    float a0 = __builtin_nontemporal_load(ea + 0);
    float a1 = __builtin_nontemporal_load(ea + 1);
    float a2 = __builtin_nontemporal_load(ea + 2);
    float a3 = __builtin_nontemporal_load(ea + 3);
    float a4 = __builtin_nontemporal_load(ea + 4);

    float p[16], q[16];
    unpack8(pa, p); unpack8(pb, p + 8);
    unpack8(qa, q); unpack8(qb, q + 8);

    float lg = sb2;
#pragma unroll
    for (int j = 0; j < 16; j++) {
        float acc = sB[j] + p[j] + q[j] +
                    a0 * sC[j] + a1 * sC[16 + j] + a2 * sC[32 + j] +
                    a3 * sC[48 + j] + a4 * sC[64 + j];
        lg += fmaxf(acc, 0.0f) * sV[j];
    }
    __builtin_nontemporal_store(lg, out + e);
}

// ---------------------------------------------------------------------------
extern "C" void kernel_launch(void* const* d_in, const int* in_sizes, int n_in,
                              void* d_out, int out_size, void* d_ws, size_t ws_size,
                              hipStream_t stream) {
    const int* seq     = (const int*)d_in[0];
    const float* xcov  = (const float*)d_in[1];
    const int* ei      = (const int*)d_in[2];
    const float* eattr = (const float*)d_in[3];
    const int* batch   = (const int*)d_in[4];
    const float* embed = (const float*)d_in[5];
    const float* w1    = (const float*)d_in[6];
    const float* b1    = (const float*)d_in[7];
    const float* w2    = (const float*)d_in[8];
    const float* b2    = (const float*)d_in[9];
    const float* we1   = (const float*)d_in[10];
    const float* be1   = (const float*)d_in[11];
    const float* we2   = (const float*)d_in[12];
    const float* be2   = (const float*)d_in[13];
    float* out         = (float*)d_out;   // fp32 output

    int N = in_sizes[1];
    int E = in_sizes[2] / 2;

    char* ws = (char*)d_ws;
    size_t off = 0;
    auto alloc = [&](size_t bytes) -> void* {
        void* p = ws + off;
        off += (bytes + 255) & ~(size_t)255;
        return p;
    };
    float* M     = (float*)alloc((size_t)N * 16 * sizeof(float));
    float* aggPQ = (float*)alloc((size_t)N * 16 * sizeof(float));   // agg, then P|Q f16
    int* bndg    = (int*)alloc((NG + 1) * sizeof(int));
    int* gcnt    = (int*)alloc(NG * 16 * sizeof(int));              // line-padded
    int2* glist  = (int2*)alloc((size_t)NG * SEGCAP * sizeof(int2));

    int gn = (N + BS - 1) / BS;
    int gp = (E + BS * 4 - 1) / (BS * 4);
    int ge = (E + BS - 1) / BS;

    encode_kernel<<<gn, BS, 0, stream>>>(seq, xcov, batch, embed, w1, b1,
                                         M, aggPQ, gcnt, bndg, N);
    prep_kernel<<<gp, BS, 0, stream>>>(ei, bndg, glist, gcnt, E);
    graph_gcn_kernel<<<NG, CBS, 0, stream>>>(glist, gcnt, bndg, M, aggPQ,
                                             w2, b2, we1);
    edge_mlp_kernel<<<ge, BS, 0, stream>>>(ei, (const char*)aggPQ, eattr,
                                           we1, be1, we2, be2, out, E);
}

// Round 11
// 471.171 us; speedup vs baseline: 1.9904x; 1.4364x over previous
//
#include <hip/hip_runtime.h>
#include <hip/hip_bf16.h>
#include <hip/hip_fp16.h>

#define BS 256
#define CBS 1024         // threads per block in per-graph GCN kernel
#define NG 64            // NUM_GRAPHS (fixed by the problem)
#define NMAX 2048        // max nodes per graph (mean 1563, sigma ~39 -> +12 sigma)
#define SEGCAP 4096      // max valid edges per graph (mean ~780)

__device__ __forceinline__ uint4 pack8(const float* f) {
    union { uint4 u; __half2 h[4]; } v;
    v.h[0] = __floats2half2_rn(f[0], f[1]);
    v.h[1] = __floats2half2_rn(f[2], f[3]);
    v.h[2] = __floats2half2_rn(f[4], f[5]);
    v.h[3] = __floats2half2_rn(f[6], f[7]);
    return v.u;
}

__device__ __forceinline__ void unpack8(uint4 u, float* f) {
    const __half2* h = (const __half2*)&u;
    float2 t;
    t = __half22float2(h[0]); f[0] = t.x; f[1] = t.y;
    t = __half22float2(h[1]); f[2] = t.x; f[3] = t.y;
    t = __half22float2(h[2]); f[4] = t.x; f[5] = t.y;
    t = __half22float2(h[3]); f[6] = t.x; f[7] = t.y;
}

// ---------------------------------------------------------------------------
// K1: zero gcnt, graph bounds from sorted batch, encode -> M1
// ---------------------------------------------------------------------------
__global__ __launch_bounds__(BS) void encode_kernel(
        const int* __restrict__ seq,
        const float* __restrict__ xcov,
        const int* __restrict__ batch,
        const float* __restrict__ embed,   // 6x16
        const float* __restrict__ w1,      // 17x16
        const float* __restrict__ b1,      // 16
        float* __restrict__ M1,
        int* __restrict__ gcnt,            // 64*16 padded
        int* __restrict__ bnd, int N) {
    __shared__ float sE[96];
    __shared__ float sW1[272];
    __shared__ float sB1[16];
    int tid = threadIdx.x;
    for (int i = tid; i < 96; i += BS) sE[i] = embed[i];
    for (int i = tid; i < 272; i += BS) sW1[i] = w1[i];
    if (tid < 16) sB1[tid] = b1[tid];
    __syncthreads();

    if (blockIdx.x == 0 && tid < NG) gcnt[tid * 16] = 0;

    int n = blockIdx.x * BS + tid;
    if (n >= N) return;

    int b = batch[n];
    if (n == 0) {
        for (int g = 0; g <= b; g++) bnd[g] = 0;
    } else {
        int pb = batch[n - 1];
        for (int g = pb + 1; g <= b; g++) bnd[g] = n;
    }
    if (n == N - 1) {
        for (int g = b + 1; g <= NG; g++) bnd[g] = N;
    }

    const int4* t4 = (const int4*)(seq + (size_t)n * 64);
    int c1 = 0, c2 = 0, c3 = 0, c4 = 0, c5 = 0;
#pragma unroll
    for (int i = 0; i < 16; i++) {
        int4 v = t4[i];
        c1 += (v.x == 1) + (v.y == 1) + (v.z == 1) + (v.w == 1);
        c2 += (v.x == 2) + (v.y == 2) + (v.z == 2) + (v.w == 2);
        c3 += (v.x == 3) + (v.y == 3) + (v.z == 3) + (v.w == 3);
        c4 += (v.x == 4) + (v.y == 4) + (v.z == 4) + (v.w == 4);
        c5 += (v.x == 5) + (v.y == 5) + (v.z == 5) + (v.w == 5);
    }
    float f1 = (float)c1, f2 = (float)c2, f3 = (float)c3, f4 = (float)c4, f5 = (float)c5;
    float tot = f1 + f2 + f3 + f4 + f5;
    float inv = 1.0f / fmaxf(tot, 1.0f);
    float h[16];
#pragma unroll
    for (int j = 0; j < 16; j++)
        h[j] = (f1 * sE[16 + j] + f2 * sE[32 + j] + f3 * sE[48 + j] +
                f4 * sE[64 + j] + f5 * sE[80 + j]) * inv;
    float xc = xcov[n];
    float o[16];
#pragma unroll
    for (int j = 0; j < 16; j++) o[j] = sB1[j] + xc * sW1[256 + j];
#pragma unroll
    for (int k = 0; k < 16; k++) {
        float hk = h[k];
#pragma unroll
        for (int j = 0; j < 16; j++) o[j] += hk * sW1[k * 16 + j];
    }
    float4* mr = (float4*)(M1 + (size_t)n * 16);
    mr[0] = make_float4(o[0], o[1], o[2], o[3]);
    mr[1] = make_float4(o[4], o[5], o[6], o[7]);
    mr[2] = make_float4(o[8], o[9], o[10], o[11]);
    mr[3] = make_float4(o[12], o[13], o[14], o[15]);
}

// ---------------------------------------------------------------------------
// K2: prep — validity via LDS bound search, bucket valid edges per graph.
// ---------------------------------------------------------------------------
__device__ __forceinline__ int find_graph(const int* bnd, int s) {
    int g = 0;
#pragma unroll
    for (int step = 32; step; step >>= 1) {
        int c = g + step;
        if (c <= NG - 1 && bnd[c] <= s) g = c;
    }
    return g;
}

__global__ __launch_bounds__(BS) void prep_kernel(
        const int* __restrict__ ei,
        const int* __restrict__ bndg,
        int2* __restrict__ glist,
        int* __restrict__ gcnt, int E) {
    __shared__ int sBnd[NG + 1];
    int tid = threadIdx.x;
    if (tid <= NG) sBnd[tid] = bndg[tid];
    __syncthreads();

    int idx = (blockIdx.x * BS + tid) * 4;
    if (idx + 3 < E) {
        int4 s4 = *(const int4*)(ei + idx);
        int4 d4 = *(const int4*)(ei + E + idx);
#pragma unroll
        for (int j = 0; j < 4; j++) {
            int s = (&s4.x)[j], d = (&d4.x)[j];
            int g = find_graph(sBnd, s);
            if (d >= sBnd[g] && d < sBnd[g + 1]) {
                int pos = atomicAdd(&gcnt[g * 16], 1);
                if (pos < SEGCAP) glist[(size_t)g * SEGCAP + pos] = make_int2(s, d);
            }
        }
    } else {
        for (int j = 0; j < 4; j++) {
            int e = idx + j;
            if (e < E) {
                int s = ei[e], d = ei[E + e];
                int g = find_graph(sBnd, s);
                if (d >= sBnd[g] && d < sBnd[g + 1]) {
                    int pos = atomicAdd(&gcnt[g * 16], 1);
                    if (pos < SEGCAP) glist[(size_t)g * SEGCAP + pos] = make_int2(s, d);
                }
            }
        }
    }
}

// ---------------------------------------------------------------------------
// K3: one block per graph. Build LDS CSR (counting sort by src), then both
// GCN layers as register-accumulated gathers. NO global atomics anywhere.
//   M2 <- relu(di*(agg1 + di*M1))@w2 + b2
//   PQ <- pack_f16( relu(di*(agg2 + di*M2)) @ we1[0:16] | @ we1[16:32] )
// ---------------------------------------------------------------------------
__global__ __launch_bounds__(CBS) void graph_gcn_kernel(
        const int2* __restrict__ glist,
        const int* __restrict__ gcnt,
        const int* __restrict__ bnd,
        const float* __restrict__ M1,
        float* __restrict__ M2,
        char* __restrict__ PQ,             // N x 64 B rows: P(32)|Q(32) f16
        const float* __restrict__ w2,      // 16x16
        const float* __restrict__ b2,      // 16
        const float* __restrict__ we1) {   // 37x16 (rows 0..31 used here)
    __shared__ int hist[NMAX];
    __shared__ int off[NMAX + 1];
    __shared__ int cur[NMAX];
    __shared__ float dinvL[NMAX];
    __shared__ int csrD[SEGCAP];
    __shared__ float sW2[256];
    __shared__ float sB2[16];
    __shared__ float sWe1[512];
    __shared__ int wsum[16];

    int tid = threadIdx.x;
    int g = blockIdx.x;
    int lo = bnd[g], hi = bnd[g + 1];
    int ng = hi - lo;
    if (ng > NMAX) ng = NMAX;   // statistically impossible; OOB guard

    for (int i = tid; i < 256; i += CBS) sW2[i] = w2[i];
    for (int i = tid; i < 512; i += CBS) sWe1[i] = we1[i];
    if (tid < 16) sB2[tid] = b2[tid];
    for (int i = tid; i < NMAX; i += CBS) hist[i] = 0;
    __syncthreads();

    if (ng <= 0) return;   // uniform whole-block exit

    int myCnt = gcnt[g * 16];
    if (myCnt > SEGCAP) myCnt = SEGCAP;
    const int2* seg = glist + (size_t)g * SEGCAP;

    // ---- degree histogram (LDS atomics) ----
    for (int j = tid; j < myCnt; j += CBS) {
        atomicAdd(&hist[seg[j].x - lo], 1);
    }
    __syncthreads();

    // ---- block exclusive prefix scan over NMAX=2048 (2 elems/thread) ----
    int i0 = 2 * tid, i1 = 2 * tid + 1;
    int v0 = hist[i0], v1 = hist[i1];
    int pair = v0 + v1;
    int lane = tid & 63, wv = tid >> 6;
    int x = pair;
#pragma unroll
    for (int o = 1; o < 64; o <<= 1) {
        int y = __shfl_up(x, o);
        if (lane >= o) x += y;
    }
    if (lane == 63) wsum[wv] = x;
    __syncthreads();
    if (wv == 0 && lane < 16) {
        int w = wsum[lane];
#pragma unroll
        for (int o = 1; o < 16; o <<= 1) {
            int y = __shfl_up(w, o);
            if (lane >= o) w += y;
        }
        wsum[lane] = w;
    }
    __syncthreads();
    int base = (wv > 0) ? wsum[wv - 1] : 0;
    int incl = base + x;
    int excl = incl - pair;
    off[i0] = excl;
    off[i1] = excl + v0;
    cur[i0] = excl;
    cur[i1] = excl + v0;
    if (tid == CBS - 1) off[NMAX] = incl;
    __syncthreads();

    // ---- dinv from degree ----
    for (int i = tid; i < ng; i += CBS) {
        float dg = (float)(off[i + 1] - off[i]) + 1.0f + 1e-8f;
        dinvL[i] = 1.0f / sqrtf(dg);
    }
    __syncthreads();

    // ---- place edges (counting sort by src) ----
    for (int j = tid; j < myCnt; j += CBS) {
        int2 e = seg[j];
        int pos = atomicAdd(&cur[e.x - lo], 1);
        csrD[pos] = e.y;
    }
    __syncthreads();

    // ---- layer 1: per-node register gather, M2 <- H1@w2+b2 ----
    for (int i = tid; i < ng; i += CBS) {
        int n = lo + i;
        int beg = off[i], end = off[i + 1];
        float di = dinvL[i];
        float acc[16];
#pragma unroll
        for (int j = 0; j < 16; j++) acc[j] = 0.f;
        for (int e = beg; e < end; e++) {
            int d = csrD[e];
            float dd = dinvL[d - lo];
            const float4* m4 = (const float4*)(M1 + (size_t)d * 16);
            float4 a = m4[0], b = m4[1], c = m4[2], q = m4[3];
            acc[0] += dd * a.x; acc[1] += dd * a.y; acc[2] += dd * a.z; acc[3] += dd * a.w;
            acc[4] += dd * b.x; acc[5] += dd * b.y; acc[6] += dd * b.z; acc[7] += dd * b.w;
            acc[8] += dd * c.x; acc[9] += dd * c.y; acc[10] += dd * c.z; acc[11] += dd * c.w;
            acc[12] += dd * q.x; acc[13] += dd * q.y; acc[14] += dd * q.z; acc[15] += dd * q.w;
        }
        const float4* mr = (const float4*)(M1 + (size_t)n * 16);
        float4 m0 = mr[0], m1 = mr[1], m2 = mr[2], m3 = mr[3];
        float m[16] = {m0.x,m0.y,m0.z,m0.w, m1.x,m1.y,m1.z,m1.w,
                       m2.x,m2.y,m2.z,m2.w, m3.x,m3.y,m3.z,m3.w};
        float h[16];
#pragma unroll
        for (int j = 0; j < 16; j++) h[j] = fmaxf(di * (acc[j] + di * m[j]), 0.0f);
        float o[16];
#pragma unroll
        for (int j = 0; j < 16; j++) o[j] = sB2[j];
#pragma unroll
        for (int k = 0; k < 16; k++) {
            float hk = h[k];
#pragma unroll
            for (int j = 0; j < 16; j++) o[j] += hk * sW2[k * 16 + j];
        }
        float4* wr = (float4*)(M2 + (size_t)n * 16);
        wr[0] = make_float4(o[0], o[1], o[2], o[3]);
        wr[1] = make_float4(o[4], o[5], o[6], o[7]);
        wr[2] = make_float4(o[8], o[9], o[10], o[11]);
        wr[3] = make_float4(o[12], o[13], o[14], o[15]);
    }
    __syncthreads();

    // ---- layer 2: gather from M2, H2 -> P|Q (f16) ----
    for (int i = tid; i < ng; i += CBS) {
        int n = lo + i;
        int beg = off[i], end = off[i + 1];
        float di = dinvL[i];
        float acc[16];
#pragma unroll
        for (int j = 0; j < 16; j++) acc[j] = 0.f;
        for (int e = beg; e < end; e++) {
            int d = csrD[e];
            float dd = dinvL[d - lo];
            const float4* m4 = (const float4*)(M2 + (size_t)d * 16);
            float4 a = m4[0], b = m4[1], c = m4[2], q = m4[3];
            acc[0] += dd * a.x; acc[1] += dd * a.y; acc[2] += dd * a.z; acc[3] += dd * a.w;
            acc[4] += dd * b.x; acc[5] += dd * b.y; acc[6] += dd * b.z; acc[7] += dd * b.w;
            acc[8] += dd * c.x; acc[9] += dd * c.y; acc[10] += dd * c.z; acc[11] += dd * c.w;
            acc[12] += dd * q.x; acc[13] += dd * q.y; acc[14] += dd * q.z; acc[15] += dd * q.w;
        }
        const float4* mr = (const float4*)(M2 + (size_t)n * 16);
        float4 m0 = mr[0], m1 = mr[1], m2 = mr[2], m3 = mr[3];
        float m[16] = {m0.x,m0.y,m0.z,m0.w, m1.x,m1.y,m1.z,m1.w,
                       m2.x,m2.y,m2.z,m2.w, m3.x,m3.y,m3.z,m3.w};
        float h[16];
#pragma unroll
        for (int j = 0; j < 16; j++) h[j] = fmaxf(di * (acc[j] + di * m[j]), 0.0f);
        float p[16], q[16];
#pragma unroll
        for (int j = 0; j < 16; j++) { p[j] = 0.f; q[j] = 0.f; }
#pragma unroll
        for (int k = 0; k < 16; k++) {
            float hk = h[k];
#pragma unroll
            for (int j = 0; j < 16; j++) {
                p[j] += hk * sWe1[k * 16 + j];
                q[j] += hk * sWe1[(16 + k) * 16 + j];
            }
        }
        uint4* pr = (uint4*)(PQ + (size_t)n * 64);
        pr[0] = pack8(p); pr[1] = pack8(p + 8);
        pr[2] = pack8(q); pr[3] = pack8(q + 8);
    }
}

// ---------------------------------------------------------------------------
// K4: edge MLP (1 edge/thread). P at row*64, Q at row*64+32.
// ---------------------------------------------------------------------------
__global__ __launch_bounds__(BS) void edge_mlp_kernel(
        const int* __restrict__ ei,
        const char* __restrict__ PQ,
        const float* __restrict__ eattr,   // E x 5 f32
        const float* __restrict__ we1,     // 37x16 f32
        const float* __restrict__ be1,     // 16
        const float* __restrict__ we2,     // 16
        const float* __restrict__ be2,     // 1
        float* __restrict__ out, int E) {
    __shared__ float sC[80];   // we1 rows 32..36
    __shared__ float sB[16];
    __shared__ float sV[16];
    __shared__ float sb2;
    int tid = threadIdx.x;
    if (tid < 80) sC[tid] = we1[512 + tid];
    if (tid < 16) { sB[tid] = be1[tid]; sV[tid] = we2[tid]; }
    if (tid == 0) sb2 = be2[0];
    __syncthreads();
    int e = blockIdx.x * BS + tid;
    if (e >= E) return;
    int s = __builtin_nontemporal_load(ei + e);
    int d = __builtin_nontemporal_load(ei + E + e);
    const uint4* pr = (const uint4*)(PQ + (size_t)s * 64);
    const uint4* qr = (const uint4*)(PQ + (size_t)d * 64 + 32);
    uint4 pa = pr[0], pb = pr[1];
    uint4 qa = qr[0], qb = qr[1];
    const float* ea = eattr + (size_t)e * 5;
    float a0 = __builtin_nontemporal_load(ea + 0);
    float a1 = __builtin_nontemporal_load(ea + 1);
    float a2 = __builtin_nontemporal_load(ea + 2);
    float a3 = __builtin_nontemporal_load(ea + 3);
    float a4 = __builtin_nontemporal_load(ea + 4);

    float p[16], q[16];
    unpack8(pa, p); unpack8(pb, p + 8);
    unpack8(qa, q); unpack8(qb, q + 8);

    float lg = sb2;
#pragma unroll
    for (int j = 0; j < 16; j++) {
        float acc = sB[j] + p[j] + q[j] +
                    a0 * sC[j] + a1 * sC[16 + j] + a2 * sC[32 + j] +
                    a3 * sC[48 + j] + a4 * sC[64 + j];
        lg += fmaxf(acc, 0.0f) * sV[j];
    }
    __builtin_nontemporal_store(lg, out + e);
}

// ---------------------------------------------------------------------------
extern "C" void kernel_launch(void* const* d_in, const int* in_sizes, int n_in,
                              void* d_out, int out_size, void* d_ws, size_t ws_size,
                              hipStream_t stream) {
    const int* seq     = (const int*)d_in[0];
    const float* xcov  = (const float*)d_in[1];
    const int* ei      = (const int*)d_in[2];
    const float* eattr = (const float*)d_in[3];
    const int* batch   = (const int*)d_in[4];
    const float* embed = (const float*)d_in[5];
    const float* w1    = (const float*)d_in[6];
    const float* b1    = (const float*)d_in[7];
    const float* w2    = (const float*)d_in[8];
    const float* b2    = (const float*)d_in[9];
    const float* we1   = (const float*)d_in[10];
    const float* be1   = (const float*)d_in[11];
    const float* we2   = (const float*)d_in[12];
    const float* be2   = (const float*)d_in[13];
    float* out         = (float*)d_out;   // fp32 output

    int N = in_sizes[1];
    int E = in_sizes[2] / 2;

    char* ws = (char*)d_ws;
    size_t off = 0;
    auto alloc = [&](size_t bytes) -> void* {
        void* p = ws + off;
        off += (bytes + 255) & ~(size_t)255;
        return p;
    };
    float* M1    = (float*)alloc((size_t)N * 16 * sizeof(float));
    float* M2    = (float*)alloc((size_t)N * 16 * sizeof(float));
    char* PQ     = (char*)alloc((size_t)N * 64);
    int* bndg    = (int*)alloc((NG + 1) * sizeof(int));
    int* gcnt    = (int*)alloc(NG * 16 * sizeof(int));
    int2* glist  = (int2*)alloc((size_t)NG * SEGCAP * sizeof(int2));

    int gn = (N + BS - 1) / BS;
    int gp = (E + BS * 4 - 1) / (BS * 4);
    int ge = (E + BS - 1) / BS;

    encode_kernel<<<gn, BS, 0, stream>>>(seq, xcov, batch, embed, w1, b1,
                                         M1, gcnt, bndg, N);
    prep_kernel<<<gp, BS, 0, stream>>>(ei, bndg, glist, gcnt, E);
    graph_gcn_kernel<<<NG, CBS, 0, stream>>>(glist, gcnt, bndg, M1, M2, PQ,
                                             w2, b2, we1);
    edge_mlp_kernel<<<ge, BS, 0, stream>>>(ei, PQ, eattr, we1, be1, we2, be2, out, E);
}

// Round 12
// 309.847 us; speedup vs baseline: 3.0268x; 1.5207x over previous
//
#include <hip/hip_runtime.h>
#include <hip/hip_bf16.h>
#include <hip/hip_fp16.h>

#define BS 256
#define BS3 256          // K3 block size: small enough to avoid VGPR spills
#define NG 64            // NUM_GRAPHS (fixed by the problem)
#define NMAX 2048        // max nodes per graph (mean 1563)
#define SEGCAP 4096      // max valid edges per graph (mean ~780)

__device__ __forceinline__ uint4 pack8(const float* f) {
    union { uint4 u; __half2 h[4]; } v;
    v.h[0] = __floats2half2_rn(f[0], f[1]);
    v.h[1] = __floats2half2_rn(f[2], f[3]);
    v.h[2] = __floats2half2_rn(f[4], f[5]);
    v.h[3] = __floats2half2_rn(f[6], f[7]);
    return v.u;
}

__device__ __forceinline__ void unpack8(uint4 u, float* f) {
    const __half2* h = (const __half2*)&u;
    float2 t;
    t = __half22float2(h[0]); f[0] = t.x; f[1] = t.y;
    t = __half22float2(h[1]); f[2] = t.x; f[3] = t.y;
    t = __half22float2(h[2]); f[4] = t.x; f[5] = t.y;
    t = __half22float2(h[3]); f[6] = t.x; f[7] = t.y;
}

// ---------------------------------------------------------------------------
// K1: zero gcnt, graph bounds from sorted batch, encode -> M1
// ---------------------------------------------------------------------------
__global__ __launch_bounds__(BS) void encode_kernel(
        const int* __restrict__ seq,
        const float* __restrict__ xcov,
        const int* __restrict__ batch,
        const float* __restrict__ embed,   // 6x16
        const float* __restrict__ w1,      // 17x16
        const float* __restrict__ b1,      // 16
        float* __restrict__ M1,
        int* __restrict__ gcnt,            // 64*16 padded
        int* __restrict__ bnd, int N) {
    __shared__ float sE[96];
    __shared__ float sW1[272];
    __shared__ float sB1[16];
    int tid = threadIdx.x;
    for (int i = tid; i < 96; i += BS) sE[i] = embed[i];
    for (int i = tid; i < 272; i += BS) sW1[i] = w1[i];
    if (tid < 16) sB1[tid] = b1[tid];
    __syncthreads();

    if (blockIdx.x == 0 && tid < NG) gcnt[tid * 16] = 0;

    int n = blockIdx.x * BS + tid;
    if (n >= N) return;

    int b = batch[n];
    if (n == 0) {
        for (int g = 0; g <= b; g++) bnd[g] = 0;
    } else {
        int pb = batch[n - 1];
        for (int g = pb + 1; g <= b; g++) bnd[g] = n;
    }
    if (n == N - 1) {
        for (int g = b + 1; g <= NG; g++) bnd[g] = N;
    }

    const int4* t4 = (const int4*)(seq + (size_t)n * 64);
    int c1 = 0, c2 = 0, c3 = 0, c4 = 0, c5 = 0;
#pragma unroll
    for (int i = 0; i < 16; i++) {
        int4 v = t4[i];
        c1 += (v.x == 1) + (v.y == 1) + (v.z == 1) + (v.w == 1);
        c2 += (v.x == 2) + (v.y == 2) + (v.z == 2) + (v.w == 2);
        c3 += (v.x == 3) + (v.y == 3) + (v.z == 3) + (v.w == 3);
        c4 += (v.x == 4) + (v.y == 4) + (v.z == 4) + (v.w == 4);
        c5 += (v.x == 5) + (v.y == 5) + (v.z == 5) + (v.w == 5);
    }
    float f1 = (float)c1, f2 = (float)c2, f3 = (float)c3, f4 = (float)c4, f5 = (float)c5;
    float tot = f1 + f2 + f3 + f4 + f5;
    float inv = 1.0f / fmaxf(tot, 1.0f);
    float h[16];
#pragma unroll
    for (int j = 0; j < 16; j++)
        h[j] = (f1 * sE[16 + j] + f2 * sE[32 + j] + f3 * sE[48 + j] +
                f4 * sE[64 + j] + f5 * sE[80 + j]) * inv;
    float xc = xcov[n];
    float o[16];
#pragma unroll
    for (int j = 0; j < 16; j++) o[j] = sB1[j] + xc * sW1[256 + j];
#pragma unroll
    for (int k = 0; k < 16; k++) {
        float hk = h[k];
#pragma unroll
        for (int j = 0; j < 16; j++) o[j] += hk * sW1[k * 16 + j];
    }
    float4* mr = (float4*)(M1 + (size_t)n * 16);
    mr[0] = make_float4(o[0], o[1], o[2], o[3]);
    mr[1] = make_float4(o[4], o[5], o[6], o[7]);
    mr[2] = make_float4(o[8], o[9], o[10], o[11]);
    mr[3] = make_float4(o[12], o[13], o[14], o[15]);
}

// ---------------------------------------------------------------------------
// K2: prep — validity via LDS bound search, bucket valid edges per graph.
// ---------------------------------------------------------------------------
__device__ __forceinline__ int find_graph(const int* bnd, int s) {
    int g = 0;
#pragma unroll
    for (int step = 32; step; step >>= 1) {
        int c = g + step;
        if (c <= NG - 1 && bnd[c] <= s) g = c;
    }
    return g;
}

__global__ __launch_bounds__(BS) void prep_kernel(
        const int* __restrict__ ei,
        const int* __restrict__ bndg,
        int2* __restrict__ glist,
        int* __restrict__ gcnt, int E) {
    __shared__ int sBnd[NG + 1];
    int tid = threadIdx.x;
    if (tid <= NG) sBnd[tid] = bndg[tid];
    __syncthreads();

    int idx = (blockIdx.x * BS + tid) * 4;
    if (idx + 3 < E) {
        int4 s4 = *(const int4*)(ei + idx);
        int4 d4 = *(const int4*)(ei + E + idx);
#pragma unroll
        for (int j = 0; j < 4; j++) {
            int s = (&s4.x)[j], d = (&d4.x)[j];
            int g = find_graph(sBnd, s);
            if (d >= sBnd[g] && d < sBnd[g + 1]) {
                int pos = atomicAdd(&gcnt[g * 16], 1);
                if (pos < SEGCAP) glist[(size_t)g * SEGCAP + pos] = make_int2(s, d);
            }
        }
    } else {
        for (int j = 0; j < 4; j++) {
            int e = idx + j;
            if (e < E) {
                int s = ei[e], d = ei[E + e];
                int g = find_graph(sBnd, s);
                if (d >= sBnd[g] && d < sBnd[g + 1]) {
                    int pos = atomicAdd(&gcnt[g * 16], 1);
                    if (pos < SEGCAP) glist[(size_t)g * SEGCAP + pos] = make_int2(s, d);
                }
            }
        }
    }
}

// ---------------------------------------------------------------------------
// K3: one block (256 thr) per graph. LDS CSR via counting sort, then both GCN
// layers as register-accumulated gathers. No global atomics, no spills.
// ---------------------------------------------------------------------------
__global__ __launch_bounds__(BS3) void graph_gcn_kernel(
        const int2* __restrict__ glist,
        const int* __restrict__ gcnt,
        const int* __restrict__ bnd,
        const float* __restrict__ M1,
        float* __restrict__ M2,
        char* __restrict__ PQ,             // N x 64 B rows: P(32)|Q(32) f16
        const float* __restrict__ w2,      // 16x16
        const float* __restrict__ b2,      // 16
        const float* __restrict__ we1) {   // 37x16 (rows 0..31 used here)
    __shared__ int hist[NMAX];
    __shared__ int off[NMAX + 1];
    __shared__ int cur[NMAX];
    __shared__ float dinvL[NMAX];
    __shared__ int csrD[SEGCAP];
    __shared__ float sW2[256];
    __shared__ float sB2[16];
    __shared__ float sWe1[512];
    __shared__ int wsum[4];

    int tid = threadIdx.x;
    int g = blockIdx.x;
    int lo = bnd[g], hi = bnd[g + 1];
    int ng = hi - lo;
    if (ng > NMAX) ng = NMAX;   // statistically impossible; OOB guard

    for (int i = tid; i < 256; i += BS3) sW2[i] = w2[i];
    for (int i = tid; i < 512; i += BS3) sWe1[i] = we1[i];
    if (tid < 16) sB2[tid] = b2[tid];
    for (int i = tid; i < NMAX; i += BS3) hist[i] = 0;
    __syncthreads();

    if (ng <= 0) return;   // uniform whole-block exit

    int myCnt = gcnt[g * 16];
    if (myCnt > SEGCAP) myCnt = SEGCAP;
    const int2* seg = glist + (size_t)g * SEGCAP;

    // ---- degree histogram (LDS atomics) ----
    for (int j = tid; j < myCnt; j += BS3) {
        atomicAdd(&hist[seg[j].x - lo], 1);
    }
    __syncthreads();

    // ---- block exclusive prefix scan over NMAX=2048 (8 elems/thread) ----
    int i0 = tid * 8;
    int lv[8];
    int s = 0;
#pragma unroll
    for (int k = 0; k < 8; k++) { lv[k] = hist[i0 + k]; s += lv[k]; }
    int lane = tid & 63, wv = tid >> 6;
    int x = s;
#pragma unroll
    for (int o = 1; o < 64; o <<= 1) {
        int y = __shfl_up(x, o);
        if (lane >= o) x += y;
    }
    if (lane == 63) wsum[wv] = x;
    __syncthreads();
    if (wv == 0 && lane < 4) {
        int w = wsum[lane];
#pragma unroll
        for (int o = 1; o < 4; o <<= 1) {
            int y = __shfl_up(w, o);
            if (lane >= o) w += y;
        }
        wsum[lane] = w;
    }
    __syncthreads();
    int base = (wv > 0) ? wsum[wv - 1] : 0;
    int excl = base + x - s;
    int run = excl;
#pragma unroll
    for (int k = 0; k < 8; k++) {
        off[i0 + k] = run;
        cur[i0 + k] = run;
        run += lv[k];
    }
    if (tid == BS3 - 1) off[NMAX] = run;
    __syncthreads();

    // ---- dinv from degree ----
    for (int i = tid; i < ng; i += BS3) {
        float dg = (float)(off[i + 1] - off[i]) + 1.0f + 1e-8f;
        dinvL[i] = 1.0f / sqrtf(dg);
    }
    __syncthreads();

    // ---- place edges (counting sort by src) ----
    for (int j = tid; j < myCnt; j += BS3) {
        int2 e = seg[j];
        int pos = atomicAdd(&cur[e.x - lo], 1);
        csrD[pos] = e.y;
    }
    __syncthreads();

    // ---- layer 1: per-node register gather, M2 <- H1@w2+b2 ----
    for (int i = tid; i < ng; i += BS3) {
        int n = lo + i;
        int beg = off[i], end = off[i + 1];
        float di = dinvL[i];
        float acc[16];
#pragma unroll
        for (int j = 0; j < 16; j++) acc[j] = 0.f;
        for (int e = beg; e < end; e++) {
            int d = csrD[e];
            float dd = dinvL[d - lo];
            const float4* m4 = (const float4*)(M1 + (size_t)d * 16);
            float4 a = m4[0], b = m4[1], c = m4[2], q = m4[3];
            acc[0] += dd * a.x; acc[1] += dd * a.y; acc[2] += dd * a.z; acc[3] += dd * a.w;
            acc[4] += dd * b.x; acc[5] += dd * b.y; acc[6] += dd * b.z; acc[7] += dd * b.w;
            acc[8] += dd * c.x; acc[9] += dd * c.y; acc[10] += dd * c.z; acc[11] += dd * c.w;
            acc[12] += dd * q.x; acc[13] += dd * q.y; acc[14] += dd * q.z; acc[15] += dd * q.w;
        }
        const float4* mr = (const float4*)(M1 + (size_t)n * 16);
        float4 m0 = mr[0], m1 = mr[1], m2 = mr[2], m3 = mr[3];
        float m[16] = {m0.x,m0.y,m0.z,m0.w, m1.x,m1.y,m1.z,m1.w,
                       m2.x,m2.y,m2.z,m2.w, m3.x,m3.y,m3.z,m3.w};
        float h[16];
#pragma unroll
        for (int j = 0; j < 16; j++) h[j] = fmaxf(di * (acc[j] + di * m[j]), 0.0f);
        float o[16];
#pragma unroll
        for (int j = 0; j < 16; j++) o[j] = sB2[j];
#pragma unroll
        for (int k = 0; k < 16; k++) {
            float hk = h[k];
#pragma unroll
            for (int j = 0; j < 16; j++) o[j] += hk * sW2[k * 16 + j];
        }
        float4* wr = (float4*)(M2 + (size_t)n * 16);
        wr[0] = make_float4(o[0], o[1], o[2], o[3]);
        wr[1] = make_float4(o[4], o[5], o[6], o[7]);
        wr[2] = make_float4(o[8], o[9], o[10], o[11]);
        wr[3] = make_float4(o[12], o[13], o[14], o[15]);
    }
    __syncthreads();

    // ---- layer 2: gather from M2, H2 -> P|Q (f16) ----
    for (int i = tid; i < ng; i += BS3) {
        int n = lo + i;
        int beg = off[i], end = off[i + 1];
        float di = dinvL[i];
        float acc[16];
#pragma unroll
        for (int j = 0; j < 16; j++) acc[j] = 0.f;
        for (int e = beg; e < end; e++) {
            int d = csrD[e];
            float dd = dinvL[d - lo];
            const float4* m4 = (const float4*)(M2 + (size_t)d * 16);
            float4 a = m4[0], b = m4[1], c = m4[2], q = m4[3];
            acc[0] += dd * a.x; acc[1] += dd * a.y; acc[2] += dd * a.z; acc[3] += dd * a.w;
            acc[4] += dd * b.x; acc[5] += dd * b.y; acc[6] += dd * b.z; acc[7] += dd * b.w;
            acc[8] += dd * c.x; acc[9] += dd * c.y; acc[10] += dd * c.z; acc[11] += dd * c.w;
            acc[12] += dd * q.x; acc[13] += dd * q.y; acc[14] += dd * q.z; acc[15] += dd * q.w;
        }
        const float4* mr = (const float4*)(M2 + (size_t)n * 16);
        float4 m0 = mr[0], m1 = mr[1], m2 = mr[2], m3 = mr[3];
        float m[16] = {m0.x,m0.y,m0.z,m0.w, m1.x,m1.y,m1.z,m1.w,
                       m2.x,m2.y,m2.z,m2.w, m3.x,m3.y,m3.z,m3.w};
        float h[16];
#pragma unroll
        for (int j = 0; j < 16; j++) h[j] = fmaxf(di * (acc[j] + di * m[j]), 0.0f);
        float p[16], q[16];
#pragma unroll
        for (int j = 0; j < 16; j++) { p[j] = 0.f; q[j] = 0.f; }
#pragma unroll
        for (int k = 0; k < 16; k++) {
            float hk = h[k];
#pragma unroll
            for (int j = 0; j < 16; j++) {
                p[j] += hk * sWe1[k * 16 + j];
                q[j] += hk * sWe1[(16 + k) * 16 + j];
            }
        }
        uint4* pr = (uint4*)(PQ + (size_t)n * 64);
        pr[0] = pack8(p); pr[1] = pack8(p + 8);
        pr[2] = pack8(q); pr[3] = pack8(q + 8);
    }
}

// ---------------------------------------------------------------------------
// K4: edge MLP (1 edge/thread). P at row*64, Q at row*64+32.
// ---------------------------------------------------------------------------
__global__ __launch_bounds__(BS) void edge_mlp_kernel(
        const int* __restrict__ ei,
        const char* __restrict__ PQ,
        const float* __restrict__ eattr,   // E x 5 f32
        const float* __restrict__ we1,     // 37x16 f32
        const float* __restrict__ be1,     // 16
        const float* __restrict__ we2,     // 16
        const float* __restrict__ be2,     // 1
        float* __restrict__ out, int E) {
    __shared__ float sC[80];   // we1 rows 32..36
    __shared__ float sB[16];
    __shared__ float sV[16];
    __shared__ float sb2;
    int tid = threadIdx.x;
    if (tid < 80) sC[tid] = we1[512 + tid];
    if (tid < 16) { sB[tid] = be1[tid]; sV[tid] = we2[tid]; }
    if (tid == 0) sb2 = be2[0];
    __syncthreads();
    int e = blockIdx.x * BS + tid;
    if (e >= E) return;
    int s = __builtin_nontemporal_load(ei + e);
    int d = __builtin_nontemporal_load(ei + E + e);
    const uint4* pr = (const uint4*)(PQ + (size_t)s * 64);
    const uint4* qr = (const uint4*)(PQ + (size_t)d * 64 + 32);
    uint4 pa = pr[0], pb = pr[1];
    uint4 qa = qr[0], qb = qr[1];
    const float* ea = eattr + (size_t)e * 5;
    float a0 = __builtin_nontemporal_load(ea + 0);
    float a1 = __builtin_nontemporal_load(ea + 1);
    float a2 = __builtin_nontemporal_load(ea + 2);
    float a3 = __builtin_nontemporal_load(ea + 3);
    float a4 = __builtin_nontemporal_load(ea + 4);

    float p[16], q[16];
    unpack8(pa, p); unpack8(pb, p + 8);
    unpack8(qa, q); unpack8(qb, q + 8);

    float lg = sb2;
#pragma unroll
    for (int j = 0; j < 16; j++) {
        float acc = sB[j] + p[j] + q[j] +
                    a0 * sC[j] + a1 * sC[16 + j] + a2 * sC[32 + j] +
                    a3 * sC[48 + j] + a4 * sC[64 + j];
        lg += fmaxf(acc, 0.0f) * sV[j];
    }
    __builtin_nontemporal_store(lg, out + e);
}

// ---------------------------------------------------------------------------
extern "C" void kernel_launch(void* const* d_in, const int* in_sizes, int n_in,
                              void* d_out, int out_size, void* d_ws, size_t ws_size,
                              hipStream_t stream) {
    const int* seq     = (const int*)d_in[0];
    const float* xcov  = (const float*)d_in[1];
    const int* ei      = (const int*)d_in[2];
    const float* eattr = (const float*)d_in[3];
    const int* batch   = (const int*)d_in[4];
    const float* embed = (const float*)d_in[5];
    const float* w1    = (const float*)d_in[6];
    const float* b1    = (const float*)d_in[7];
    const float* w2    = (const float*)d_in[8];
    const float* b2    = (const float*)d_in[9];
    const float* we1   = (const float*)d_in[10];
    const float* be1   = (const float*)d_in[11];
    const float* we2   = (const float*)d_in[12];
    const float* be2   = (const float*)d_in[13];
    float* out         = (float*)d_out;   // fp32 output

    int N = in_sizes[1];
    int E = in_sizes[2] / 2;

    char* ws = (char*)d_ws;
    size_t off = 0;
    auto alloc = [&](size_t bytes) -> void* {
        void* p = ws + off;
        off += (bytes + 255) & ~(size_t)255;
        return p;
    };
    float* M1    = (float*)alloc((size_t)N * 16 * sizeof(float));
    float* M2    = (float*)alloc((size_t)N * 16 * sizeof(float));
    char* PQ     = (char*)alloc((size_t)N * 64);
    int* bndg    = (int*)alloc((NG + 1) * sizeof(int));
    int* gcnt    = (int*)alloc(NG * 16 * sizeof(int));
    int2* glist  = (int2*)alloc((size_t)NG * SEGCAP * sizeof(int2));

    int gn = (N + BS - 1) / BS;
    int gp = (E + BS * 4 - 1) / (BS * 4);
    int ge = (E + BS - 1) / BS;

    encode_kernel<<<gn, BS, 0, stream>>>(seq, xcov, batch, embed, w1, b1,
                                         M1, gcnt, bndg, N);
    prep_kernel<<<gp, BS, 0, stream>>>(ei, bndg, glist, gcnt, E);
    graph_gcn_kernel<<<NG, BS3, 0, stream>>>(glist, gcnt, bndg, M1, M2, PQ,
                                             w2, b2, we1);
    edge_mlp_kernel<<<ge, BS, 0, stream>>>(ei, PQ, eattr, we1, be1, we2, be2, out, E);
}